// Round 1
// baseline (4362.910 us; speedup 1.0000x reference)
//
#include <hip/hip_runtime.h>
#include <algorithm>
#include <cstdint>

// Problem constants (fixed by setup_inputs)
#define Nn 8192
#define Mm 8192
#define Dd 512
#define Cc 128

#define BT 128   // block tile (n and m)
#define TK 16    // k-chunk

// ---- workspace layout (bytes) ----
// Sr double[8192], Sc double[8192] (sums -> reciprocals in place)
// ghist uint[65536], ctr uint[16] {0:cand_count,1:final_count,2:gthresh,3:tb16}
// final uint4[4096], cand uint4[CAP]
#define WS_SR     0u
#define WS_SC     65536u
#define WS_GHIST  131072u
#define WS_CTR    393216u
#define WS_FINAL  393472u
#define WS_CAND   459008u
#define FCAP      4096u

// ---------------------------------------------------------------------------
// Kernel 1: inner GEMM -> e = exp(2*inner-2) -> row/col sums (f64 atomics)
// ---------------------------------------------------------------------------
__global__ __launch_bounds__(256, 3) void k_sums(const float* __restrict__ A,
                                                 const float* __restrict__ B,
                                                 double* __restrict__ Sr,
                                                 double* __restrict__ Sc) {
  __shared__ float SA[TK][BT];
  __shared__ float SB[TK][BT];
  __shared__ double rsum[BT];
  __shared__ double csum[BT];
  const int tid = threadIdx.x;
  const int tx = tid & 15, ty = tid >> 4;
  const int n0 = blockIdx.y * BT, m0 = blockIdx.x * BT;
  const int lrow = tid >> 1;        // 0..127
  const int lk8  = (tid & 1) * 8;   // 0 or 8

  float acc[8][8];
#pragma unroll
  for (int i = 0; i < 8; ++i)
#pragma unroll
    for (int j = 0; j < 8; ++j) acc[i][j] = 0.0f;

  for (int k0 = 0; k0 < Dd; k0 += TK) {
    const float4 a0 = *(const float4*)(A + (size_t)(n0 + lrow) * Dd + k0 + lk8);
    const float4 a1 = *(const float4*)(A + (size_t)(n0 + lrow) * Dd + k0 + lk8 + 4);
    const float4 b0 = *(const float4*)(B + (size_t)(m0 + lrow) * Dd + k0 + lk8);
    const float4 b1 = *(const float4*)(B + (size_t)(m0 + lrow) * Dd + k0 + lk8 + 4);
    __syncthreads();
    {
      const float ar[8] = {a0.x,a0.y,a0.z,a0.w,a1.x,a1.y,a1.z,a1.w};
      const float br[8] = {b0.x,b0.y,b0.z,b0.w,b1.x,b1.y,b1.z,b1.w};
#pragma unroll
      for (int s = 0; s < 8; ++s) { SA[lk8 + s][lrow] = ar[s]; SB[lk8 + s][lrow] = br[s]; }
    }
    __syncthreads();
#pragma unroll
    for (int kk = 0; kk < TK; ++kk) {
      const float4 av0 = *(const float4*)&SA[kk][ty * 8];
      const float4 av1 = *(const float4*)&SA[kk][ty * 8 + 4];
      const float4 bv0 = *(const float4*)&SB[kk][tx * 8];
      const float4 bv1 = *(const float4*)&SB[kk][tx * 8 + 4];
      const float a[8] = {av0.x,av0.y,av0.z,av0.w,av1.x,av1.y,av1.z,av1.w};
      const float b[8] = {bv0.x,bv0.y,bv0.z,bv0.w,bv1.x,bv1.y,bv1.z,bv1.w};
#pragma unroll
      for (int i = 0; i < 8; ++i)
#pragma unroll
        for (int j = 0; j < 8; ++j) acc[i][j] = fmaf(a[i], b[j], acc[i][j]);
    }
  }

  if (tid < BT) { rsum[tid] = 0.0; csum[tid] = 0.0; }
  __syncthreads();
  float rp[8], cp[8];
#pragma unroll
  for (int i = 0; i < 8; ++i) { rp[i] = 0.0f; cp[i] = 0.0f; }
#pragma unroll
  for (int i = 0; i < 8; ++i)
#pragma unroll
    for (int j = 0; j < 8; ++j) {
      const float ev = expf(2.0f * acc[i][j] - 2.0f);
      rp[i] += ev;
      cp[j] += ev;
    }
#pragma unroll
  for (int i = 0; i < 8; ++i) atomicAdd(&rsum[ty * 8 + i], (double)rp[i]);
#pragma unroll
  for (int j = 0; j < 8; ++j) atomicAdd(&csum[tx * 8 + j], (double)cp[j]);
  __syncthreads();
  if (tid < BT) {
    atomicAdd(&Sr[n0 + tid], rsum[tid]);
    atomicAdd(&Sc[m0 + tid], csum[tid]);
  }
}

// ---------------------------------------------------------------------------
// Kernel 2: Sr/Sc -> reciprocals in place
// ---------------------------------------------------------------------------
__global__ void k_recip(double* __restrict__ Sr, double* __restrict__ Sc) {
  const int i = blockIdx.x * 256 + threadIdx.x;
  if (i < Nn) Sr[i] = 1.0 / Sr[i];
  if (i < Mm) Sc[i] = 1.0 / Sc[i];
}

// ---------------------------------------------------------------------------
// Kernel 3: recompute inner + overlap GEMMs, f64 score, per-tile candidate push
// ---------------------------------------------------------------------------
__global__ __launch_bounds__(256, 2) void k_score(const float* __restrict__ A,
                                                  const float* __restrict__ B,
                                                  const float* __restrict__ C0,
                                                  const float* __restrict__ C1,
                                                  const double* __restrict__ invSr,
                                                  const double* __restrict__ invSc,
                                                  uint4* __restrict__ cand,
                                                  unsigned int* __restrict__ ctr,
                                                  unsigned int cap) {
  __shared__ float SA[TK][BT];
  __shared__ float SB[TK][BT];
  __shared__ unsigned int h1[256];
  __shared__ unsigned int scn[256];
  __shared__ unsigned int sh_misc[4];
  const int tid = threadIdx.x;
  const int tx = tid & 15, ty = tid >> 4;
  const int n0 = blockIdx.y * BT, m0 = blockIdx.x * BT;

  // ---------------- inner GEMM, two-level f32 accumulation ----------------
  float acc2[8][8];
#pragma unroll
  for (int i = 0; i < 8; ++i)
#pragma unroll
    for (int j = 0; j < 8; ++j) acc2[i][j] = 0.0f;
  {
    const int lrow = tid >> 1;
    const int lk8  = (tid & 1) * 8;
    for (int k0 = 0; k0 < Dd; k0 += TK) {
      const float4 a0 = *(const float4*)(A + (size_t)(n0 + lrow) * Dd + k0 + lk8);
      const float4 a1 = *(const float4*)(A + (size_t)(n0 + lrow) * Dd + k0 + lk8 + 4);
      const float4 b0 = *(const float4*)(B + (size_t)(m0 + lrow) * Dd + k0 + lk8);
      const float4 b1 = *(const float4*)(B + (size_t)(m0 + lrow) * Dd + k0 + lk8 + 4);
      __syncthreads();
      {
        const float ar[8] = {a0.x,a0.y,a0.z,a0.w,a1.x,a1.y,a1.z,a1.w};
        const float br[8] = {b0.x,b0.y,b0.z,b0.w,b1.x,b1.y,b1.z,b1.w};
#pragma unroll
        for (int s = 0; s < 8; ++s) { SA[lk8 + s][lrow] = ar[s]; SB[lk8 + s][lrow] = br[s]; }
      }
      __syncthreads();
      float acc1[8][8];
#pragma unroll
      for (int i = 0; i < 8; ++i)
#pragma unroll
        for (int j = 0; j < 8; ++j) acc1[i][j] = 0.0f;
#pragma unroll
      for (int kk = 0; kk < TK; ++kk) {
        const float4 av0 = *(const float4*)&SA[kk][ty * 8];
        const float4 av1 = *(const float4*)&SA[kk][ty * 8 + 4];
        const float4 bv0 = *(const float4*)&SB[kk][tx * 8];
        const float4 bv1 = *(const float4*)&SB[kk][tx * 8 + 4];
        const float a[8] = {av0.x,av0.y,av0.z,av0.w,av1.x,av1.y,av1.z,av1.w};
        const float b[8] = {bv0.x,bv0.y,bv0.z,bv0.w,bv1.x,bv1.y,bv1.z,bv1.w};
#pragma unroll
        for (int i = 0; i < 8; ++i)
#pragma unroll
          for (int j = 0; j < 8; ++j) acc1[i][j] = fmaf(a[i], b[j], acc1[i][j]);
      }
#pragma unroll
      for (int i = 0; i < 8; ++i)
#pragma unroll
        for (int j = 0; j < 8; ++j) acc2[i][j] += acc1[i][j];
    }
  }

  // ---------------- overlap GEMM (cas0:[C][N], cas1:[C][M]) ----------------
  float ov2[8][8];
#pragma unroll
  for (int i = 0; i < 8; ++i)
#pragma unroll
    for (int j = 0; j < 8; ++j) ov2[i][j] = 0.0f;
  {
    const int sc = tid >> 4;          // c within chunk, 0..15
    const int sn = (tid & 15) * 8;    // column offset
    for (int c0 = 0; c0 < Cc; c0 += TK) {
      const float4 a0 = *(const float4*)(C0 + (size_t)(c0 + sc) * Nn + n0 + sn);
      const float4 a1 = *(const float4*)(C0 + (size_t)(c0 + sc) * Nn + n0 + sn + 4);
      const float4 b0 = *(const float4*)(C1 + (size_t)(c0 + sc) * Mm + m0 + sn);
      const float4 b1 = *(const float4*)(C1 + (size_t)(c0 + sc) * Mm + m0 + sn + 4);
      __syncthreads();
      *(float4*)&SA[sc][sn] = a0; *(float4*)&SA[sc][sn + 4] = a1;
      *(float4*)&SB[sc][sn] = b0; *(float4*)&SB[sc][sn + 4] = b1;
      __syncthreads();
      float ov1[8][8];
#pragma unroll
      for (int i = 0; i < 8; ++i)
#pragma unroll
        for (int j = 0; j < 8; ++j) ov1[i][j] = 0.0f;
#pragma unroll
      for (int kk = 0; kk < TK; ++kk) {
        const float4 av0 = *(const float4*)&SA[kk][ty * 8];
        const float4 av1 = *(const float4*)&SA[kk][ty * 8 + 4];
        const float4 bv0 = *(const float4*)&SB[kk][tx * 8];
        const float4 bv1 = *(const float4*)&SB[kk][tx * 8 + 4];
        const float a[8] = {av0.x,av0.y,av0.z,av0.w,av1.x,av1.y,av1.z,av1.w};
        const float b[8] = {bv0.x,bv0.y,bv0.z,bv0.w,bv1.x,bv1.y,bv1.z,bv1.w};
#pragma unroll
        for (int i = 0; i < 8; ++i)
#pragma unroll
          for (int j = 0; j < 8; ++j) ov1[i][j] = fmaf(a[i], b[j], ov1[i][j]);
      }
#pragma unroll
      for (int i = 0; i < 8; ++i)
#pragma unroll
        for (int j = 0; j < 8; ++j) ov2[i][j] += ov1[i][j];
    }
  }

  // ---------------- f64 score + f32 key bits ----------------
  double isr[8], isc[8];
#pragma unroll
  for (int i = 0; i < 8; ++i) isr[i] = invSr[n0 + ty * 8 + i];
#pragma unroll
  for (int j = 0; j < 8; ++j) isc[j] = invSc[m0 + tx * 8 + j];

  unsigned int sbits[8][8];
#pragma unroll
  for (int i = 0; i < 8; ++i)
#pragma unroll
    for (int j = 0; j < 8; ++j) {
      const double e = exp(2.0 * (double)acc2[i][j] - 2.0);
      const double s = e * e * isr[i] * isc[j] * (double)ov2[i][j];
      sbits[i][j] = __float_as_uint((float)s);  // s > 0 -> monotone bits
    }

  // ---------------- two-level (8+8 bit) block histogram threshold ----------
  h1[tid] = 0;
  __syncthreads();
#pragma unroll
  for (int i = 0; i < 8; ++i)
#pragma unroll
    for (int j = 0; j < 8; ++j) atomicAdd(&h1[sbits[i][j] >> 24], 1u);
  __syncthreads();
  if (tid == 0) {
    unsigned cum = 0, cb = 0, above = 0;
    for (int b = 255; b >= 0; --b) {
      const unsigned nc = cum + h1[b];
      if (nc >= 256u) { cb = (unsigned)b; above = cum; break; }
      cum = nc;
    }
    sh_misc[0] = cb; sh_misc[1] = above;
  }
  __syncthreads();
  const unsigned cb = sh_misc[0], above = sh_misc[1];
  __syncthreads();
  h1[tid] = 0;
  __syncthreads();
#pragma unroll
  for (int i = 0; i < 8; ++i)
#pragma unroll
    for (int j = 0; j < 8; ++j)
      if ((sbits[i][j] >> 24) == cb) atomicAdd(&h1[(sbits[i][j] >> 16) & 0xFFu], 1u);
  __syncthreads();
  if (tid == 0) {
    unsigned cum = above, tb = cb << 8;
    for (int b = 255; b >= 0; --b) {
      cum += h1[b];
      if (cum >= 256u) { tb = (cb << 8) | (unsigned)b; break; }
    }
    const unsigned old = atomicMax(&ctr[2], tb);  // device-scope running bound
    sh_misc[2] = tb > old ? tb : old;
  }
  __syncthreads();
  const unsigned tb16 = sh_misc[2];

  // ---------------- push candidates (block-aggregated offsets) -------------
  unsigned cnt = 0;
#pragma unroll
  for (int i = 0; i < 8; ++i)
#pragma unroll
    for (int j = 0; j < 8; ++j) cnt += ((sbits[i][j] >> 16) >= tb16) ? 1u : 0u;
  scn[tid] = cnt;
  __syncthreads();
  if (tid == 0) {
    unsigned run = 0;
    for (int t = 0; t < 256; ++t) { const unsigned c = scn[t]; scn[t] = run; run += c; }
    sh_misc[3] = atomicAdd(&ctr[0], run);
  }
  __syncthreads();
  unsigned pos = sh_misc[3] + scn[tid];
#pragma unroll
  for (int i = 0; i < 8; ++i)
#pragma unroll
    for (int j = 0; j < 8; ++j) {
      if ((sbits[i][j] >> 16) >= tb16) {
        if (pos < cap) {
          const double e = exp(2.0 * (double)acc2[i][j] - 2.0);
          const double s = e * e * isr[i] * isc[j] * (double)ov2[i][j];
          const unsigned long long db = (unsigned long long)__double_as_longlong(s);
          const unsigned idxv = ((unsigned)(n0 + ty * 8 + i) << 13) | (unsigned)(m0 + tx * 8 + j);
          cand[pos] = make_uint4((unsigned)(db & 0xFFFFFFFFull),
                                 (unsigned)(db >> 32), idxv, sbits[i][j]);
        }
        ++pos;
      }
    }
}

// ---------------------------------------------------------------------------
// Kernel 4: global 65536-bin histogram of candidate keys
// ---------------------------------------------------------------------------
__global__ void k_ghist(const uint4* __restrict__ cand,
                        const unsigned int* __restrict__ ctr,
                        unsigned int cap, unsigned int* __restrict__ ghist) {
  const unsigned n = min(ctr[0], cap);
  const unsigned stride = gridDim.x * blockDim.x;
  for (unsigned i = blockIdx.x * blockDim.x + threadIdx.x; i < n; i += stride)
    atomicAdd(&ghist[cand[i].w >> 16], 1u);
}

// ---------------------------------------------------------------------------
// Kernel 5: find global threshold bin (suffix count >= 256)
// ---------------------------------------------------------------------------
__global__ __launch_bounds__(256) void k_thresh(const unsigned int* __restrict__ ghist,
                                                unsigned int* __restrict__ ctr) {
  __shared__ unsigned int gsum[256];
  const int tid = threadIdx.x;
  unsigned s = 0;
  const int base = tid * 256;
  for (int b = 0; b < 256; ++b) s += ghist[base + b];
  gsum[tid] = s;
  __syncthreads();
  if (tid == 0) {
    unsigned cum = 0, g = 0, above = 0;
    for (int t = 255; t >= 0; --t) {
      const unsigned nc = cum + gsum[t];
      if (nc >= 256u) { g = (unsigned)t; above = cum; break; }
      cum = nc;
    }
    unsigned tb = g * 256u, c2 = above;
    for (int b = (int)g * 256 + 255; b >= (int)g * 256; --b) {
      c2 += ghist[b];
      if (c2 >= 256u) { tb = (unsigned)b; break; }
    }
    ctr[3] = tb;
  }
}

// ---------------------------------------------------------------------------
// Kernel 6: collect survivors
// ---------------------------------------------------------------------------
__global__ void k_collect(const uint4* __restrict__ cand,
                          unsigned int* __restrict__ ctr,
                          unsigned int cap, uint4* __restrict__ fin) {
  const unsigned n = min(ctr[0], cap);
  const unsigned tb = ctr[3];
  const unsigned stride = gridDim.x * blockDim.x;
  for (unsigned i = blockIdx.x * blockDim.x + threadIdx.x; i < n; i += stride) {
    const uint4 c = cand[i];
    if ((c.w >> 16) >= tb) {
      const unsigned p = atomicAdd(&ctr[1], 1u);
      if (p < FCAP) fin[p] = c;
    }
  }
}

// ---------------------------------------------------------------------------
// Kernel 7: single-block bitonic sort (f64-bits desc, idx asc) -> outputs
// ---------------------------------------------------------------------------
__global__ __launch_bounds__(256) void k_sort(const uint4* __restrict__ fin,
                                              const unsigned int* __restrict__ ctr,
                                              float* __restrict__ out) {
  __shared__ unsigned long long kk[FCAP];
  __shared__ unsigned int id[FCAP];
  const int tid = threadIdx.x;
  const unsigned n = min(ctr[1], FCAP);
  for (unsigned i = tid; i < FCAP; i += 256) {
    if (i < n) {
      const uint4 c = fin[i];
      kk[i] = ((unsigned long long)c.y << 32) | (unsigned long long)c.x;
      id[i] = c.z;
    } else {
      kk[i] = 0ull;
      id[i] = 0xFFFFFFFFu;
    }
  }
  __syncthreads();
  for (unsigned k2 = 2; k2 <= FCAP; k2 <<= 1) {
    for (unsigned j = k2 >> 1; j > 0; j >>= 1) {
      for (unsigned i = tid; i < FCAP; i += 256) {
        const unsigned l = i ^ j;
        if (l > i) {
          const unsigned long long ka = kk[i], kb = kk[l];
          const unsigned ia = id[i], ib = id[l];
          const bool aBefore = (ka > kb) || (ka == kb && ia < ib);
          const bool dsc = (i & k2) == 0;
          const bool sw = dsc ? !aBefore : aBefore;
          if (sw) { kk[i] = kb; kk[l] = ka; id[i] = ib; id[l] = ia; }
        }
      }
      __syncthreads();
    }
  }
  if (tid < 256) {
    const unsigned long long kv = kk[tid];
    const unsigned ix = id[tid];
    const double s = __longlong_as_double((long long)kv);
    out[tid]        = (float)(ix >> 13);      // ref_corr_indices
    out[256 + tid]  = (float)(ix & 8191u);    // src_corr_indices
    out[512 + tid]  = (float)s;               // corr_scores
  }
}

// ---------------------------------------------------------------------------
extern "C" void kernel_launch(void* const* d_in, const int* in_sizes, int n_in,
                              void* d_out, int out_size, void* d_ws, size_t ws_size,
                              hipStream_t stream) {
  (void)in_sizes; (void)n_in; (void)out_size;
  const float* ref = (const float*)d_in[0];
  const float* src = (const float*)d_in[1];
  const float* c0  = (const float*)d_in[2];
  const float* c1  = (const float*)d_in[3];
  char* ws = (char*)d_ws;
  double* Sr = (double*)(ws + WS_SR);
  double* Sc = (double*)(ws + WS_SC);
  unsigned int* ghist = (unsigned int*)(ws + WS_GHIST);
  unsigned int* ctr   = (unsigned int*)(ws + WS_CTR);
  uint4* fin  = (uint4*)(ws + WS_FINAL);
  uint4* cand = (uint4*)(ws + WS_CAND);
  unsigned int cap = 0;
  if (ws_size > (size_t)WS_CAND + 16)
    cap = (unsigned int)std::min<size_t>((ws_size - WS_CAND) / 16, (size_t)(8u << 20));

  // zero Sr, Sc, ghist, ctr
  hipMemsetAsync(d_ws, 0, WS_FINAL, stream);

  dim3 grid(Mm / BT, Nn / BT);
  k_sums<<<grid, 256, 0, stream>>>(ref, src, Sr, Sc);
  k_recip<<<32, 256, 0, stream>>>(Sr, Sc);
  k_score<<<grid, 256, 0, stream>>>(ref, src, c0, c1, Sr, Sc, cand, ctr, cap);
  k_ghist<<<256, 256, 0, stream>>>(cand, ctr, cap, ghist);
  k_thresh<<<1, 256, 0, stream>>>(ghist, ctr);
  k_collect<<<256, 256, 0, stream>>>(cand, ctr, cap, fin);
  k_sort<<<1, 256, 0, stream>>>(fin, ctr, (float*)d_out);
}